// Round 7
// baseline (262.862 us; speedup 1.0000x reference)
//
#include <hip/hip_runtime.h>
#include <hip/hip_fp16.h>

#define NEG_SLOPE 0.2f

static __device__ __forceinline__ unsigned short f2bf(float f) {
    unsigned u = __float_as_uint(f);
    unsigned r = (u + 0x7fffu + ((u >> 16) & 1u)) >> 16;   // RNE
    return (unsigned short)r;
}
static __device__ __forceinline__ float bflo(unsigned z) {
    return __uint_as_float((z & 0xffffu) << 16);
}
static __device__ __forceinline__ float bfhi(unsigned z) {
    return __uint_as_float(z & 0xffff0000u);
}

#define PREP_B 66   // blocks for prep part (128*128+512 = 16896 threads)

// ---- K1: prep (Wc, avec)  ||  count (degree histogram) ----
__global__ __launch_bounds__(256) void prep_count_kernel(
    const float* __restrict__ Wl, const float* __restrict__ Wout,
    const float* __restrict__ attL, const float* __restrict__ attR,
    float* __restrict__ Wc, float* __restrict__ avec,
    const int* __restrict__ ei, int E, int Etot, int* __restrict__ cnt)
{
    int bid = blockIdx.x;
    if (bid < PREP_B) {
        int idx = bid * 256 + threadIdx.x;
        if (idx < 128 * 128) {
            int k = idx >> 7, c = idx & 127;
            int h = c >> 6, cc = c & 63;
            const float* wl = Wl + k * 128 + h * 64;
            const float* wo = Wout + (h * 64) * 64 + cc;
            float s = 0.f;
#pragma unroll 8
            for (int m = 0; m < 64; ++m) s += wl[m] * wo[m * 64];
            Wc[k * 128 + c] = s;
        } else if (idx < 128 * 128 + 512) {
            int r = idx - 128 * 128;
            int k = r >> 2, t = r & 3;
            int h = t & 1;
            const float* av = ((t < 2) ? attL : attR) + h * 64;
            const float* wl = Wl + k * 128 + h * 64;
            float s = 0.f;
#pragma unroll 8
            for (int m = 0; m < 64; ++m) s += wl[m] * av[m];
            avec[k * 4 + t] = s;
        }
    } else {
        int e = (bid - PREP_B) * 256 + threadIdx.x;
        if (e >= Etot) return;
        int dst = (e < E) ? ei[E + e] : (e - E);
        atomicAdd(&cnt[dst], 1);
    }
}

// ---- K2: zproj (Z bf16, AL/AR)  ||  scan1 (per-256-chunk exclusive scan) ----
__global__ __launch_bounds__(256, 4) void zproj_scan_kernel(
    const float* __restrict__ x, const float* __restrict__ Wc,
    const float* __restrict__ avec, int N, int ZB,
    unsigned short* __restrict__ Z, float* __restrict__ AL, float* __restrict__ AR,
    const int* __restrict__ cnt, int* __restrict__ off, int* __restrict__ chs)
{
    __shared__ float xs[64 * 136];   // zproj x tile; scan1 reuses as int[256]
    __shared__ float avs[128 * 4];
    const int tid = threadIdx.x;

    if ((int)blockIdx.x >= ZB) {
        // ----- scan1 -----
        int blk = blockIdx.x - ZB;
        int* s = (int*)xs;
        int i = blk * 256 + tid;
        int v = (i < N) ? cnt[i] : 0;
        s[tid] = v; __syncthreads();
#pragma unroll
        for (int o = 1; o < 256; o <<= 1) {
            int add = (tid >= o) ? s[tid - o] : 0;
            __syncthreads();
            s[tid] += add;
            __syncthreads();
        }
        if (i < N) off[i] = s[tid] - v;     // exclusive within chunk
        if (tid == 255) chs[blk] = s[255];  // chunk total
        return;
    }

    // ----- zproj -----
    const int row0 = blockIdx.x * 64;
    const float4* x4 = (const float4*)x;
#pragma unroll
    for (int it = 0; it < 8; ++it) {
        int f4 = it * 256 + tid;           // 2048 float4 = 64 rows x 32 chunks
        int r = f4 >> 5, kq = f4 & 31;
        int rsrc = row0 + r; if (rsrc >= N) rsrc = N - 1;
        float4 v = x4[(size_t)rsrc * 32 + kq];
        *(float4*)&xs[r * 136 + kq * 4] = v;
    }
    if (tid < 128) *(float4*)&avs[tid * 4] = *(const float4*)&avec[tid * 4];
    __syncthreads();

    const int cg = tid & 31;   // cols cg*4..+3
    const int rg = tid >> 5;   // rows rg*8..+7
    const int c0 = cg * 4, r0 = rg * 8;
    float acc[8][4] = {};
    const float* wp = Wc + c0;
    for (int kc = 0; kc < 32; ++kc) {
        int k = kc * 4;
        float4 w0 = *(const float4*)&wp[(k + 0) * 128];
        float4 w1 = *(const float4*)&wp[(k + 1) * 128];
        float4 w2 = *(const float4*)&wp[(k + 2) * 128];
        float4 w3 = *(const float4*)&wp[(k + 3) * 128];
#pragma unroll
        for (int i = 0; i < 8; ++i) {
            float4 xv = *(const float4*)&xs[(r0 + i) * 136 + k];
            acc[i][0] += xv.x * w0.x + xv.y * w1.x + xv.z * w2.x + xv.w * w3.x;
            acc[i][1] += xv.x * w0.y + xv.y * w1.y + xv.z * w2.y + xv.w * w3.y;
            acc[i][2] += xv.x * w0.z + xv.y * w1.z + xv.z * w2.z + xv.w * w3.z;
            acc[i][3] += xv.x * w0.w + xv.y * w1.w + xv.z * w2.w + xv.w * w3.w;
        }
    }
#pragma unroll
    for (int i = 0; i < 8; ++i) {
        int row = row0 + r0 + i;
        if (row < N) {
            ushort4 zz;
            zz.x = f2bf(acc[i][0]); zz.y = f2bf(acc[i][1]);
            zz.z = f2bf(acc[i][2]); zz.w = f2bf(acc[i][3]);
            *(ushort4*)(Z + (size_t)row * 128 + c0) = zz;
        }
    }
    // alpha tail: one dot per thread (row = tid>>2, type = tid&3)
    {
        int row = tid >> 2, t = tid & 3;
        const float* xr = &xs[row * 136];
        float s = 0.f;
#pragma unroll 8
        for (int k = 0; k < 128; k += 4) {
            float4 xv = *(const float4*)&xr[k];
            s += xv.x * avs[(k + 0) * 4 + t] + xv.y * avs[(k + 1) * 4 + t]
               + xv.z * avs[(k + 2) * 4 + t] + xv.w * avs[(k + 3) * 4 + t];
        }
        int grow = row0 + row;
        if (grow < N) {
            if (t < 2) AL[grow * 2 + t] = s;
            else       AR[grow * 2 + (t - 2)] = s;
        }
    }
}

// ---- K3: scan chunk totals; emit chunkbase[C+1] and padded chunk cursors ----
__global__ __launch_bounds__(256) void scan2x(
    int* __restrict__ chs, int nb, int N, int Etot,
    const int* __restrict__ off, int* __restrict__ chunkbase,
    int* __restrict__ chunkptr)
{
    __shared__ int s[256];
    __shared__ int ex[256];
    int t = threadIdx.x;
    int v = (t < nb) ? chs[t] : 0;
    s[t] = v; __syncthreads();
#pragma unroll
    for (int o = 1; o < 256; o <<= 1) {
        int add = (t >= o) ? s[t - o] : 0;
        __syncthreads();
        s[t] += add;
        __syncthreads();
    }
    int excl = s[t] - v;
    ex[t] = excl;
    if (t < nb) chs[t] = excl;
    __syncthreads();
    int C = (N + 63) >> 6;
    for (int c = t; c <= C; c += 256) {
        int node = c << 6;
        int base = (node >= N) ? Etot : (ex[node >> 8] + off[node]);
        chunkbase[c] = base;
        if (c < C) chunkptr[c * 16] = base;
    }
}

// ---- K4: fill2 — append {src<<6|dstlo, half2(ex0,ex1)} into chunk bucket ----
__global__ void fill2_kernel(const int* __restrict__ ei, int E, int Etot,
                             const float* __restrict__ AL, const float* __restrict__ AR,
                             int* __restrict__ chunkptr, uint2* __restrict__ edg)
{
    int e = blockIdx.x * 256 + threadIdx.x;
    if (e >= Etot) return;
    int src, dst;
    if (e < E) { src = ei[e]; dst = ei[E + e]; }
    else       { src = e - E; dst = e - E; }
    float2 al = *(const float2*)&AL[src * 2];
    float2 ar = *(const float2*)&AR[dst * 2];
    float e0 = al.x + ar.x, e1 = al.y + ar.y;
    e0 = (e0 < 0.f) ? NEG_SLOPE * e0 : e0;
    e1 = (e1 < 0.f) ? NEG_SLOPE * e1 : e1;
    int pos = atomicAdd(&chunkptr[(dst >> 6) * 16], 1);
    __half2 hh = __floats2half2_rn(__expf(e0), __expf(e1));
    uint2 rec;
    rec.x = ((unsigned)src << 6) | (unsigned)(dst & 63);
    rec.y = *(unsigned*)&hh;
    edg[pos] = rec;
}

// ---- K5: sort — block per 64-node chunk, scatter to exact CSR position ----
__global__ __launch_bounds__(256) void sort_kernel(
    const int* __restrict__ chunkbase, const int* __restrict__ chs,
    const int* __restrict__ off, const uint2* __restrict__ edg,
    uint2* __restrict__ edg2, int N)
{
    __shared__ int ptr[64];
    int c = blockIdx.x;
    int t = threadIdx.x;
    if (t < 64) {
        int n = c * 64 + t;
        ptr[t] = (n < N) ? (chs[n >> 8] + off[n]) : 0;
    }
    int base = chunkbase[c], endb = chunkbase[c + 1];
    __syncthreads();
    for (int i = base + t; i < endb; i += 256) {
        uint2 r = edg[i];
        int dlo = r.x & 63;
        int p = atomicAdd(&ptr[dlo], 1);
        edg2[p] = make_uint2(r.x >> 6, r.y);
    }
}

// ---- K6: agg — wave/node, 16-lane groups, 8 edges in flight ----
__global__ __launch_bounds__(256) void agg_kernel(
    const int* __restrict__ off, const int* __restrict__ chs,
    const int* __restrict__ cnt, const uint2* __restrict__ edg2,
    const unsigned short* __restrict__ Z, const float* __restrict__ bias,
    float* __restrict__ out, int N)
{
    int wid = threadIdx.x >> 6, lane = threadIdx.x & 63;
    int node = blockIdx.x * 4 + wid;
    if (node >= N) return;
    int start = chs[node >> 8] + off[node];
    int end = start + cnt[node];
    int g  = lane >> 4;              // edge slot 0..3
    int l4 = lane & 15;              // 16B chunk of the 256B Z row
    int h  = l4 >> 3;                // head owning these channels
    float a[8] = {};
    float ws = 0.f;
    uint2 rA = make_uint2(0u, 0u), rB = make_uint2(0u, 0u);
    if (start + g < end)     rA = edg2[start + g];
    if (start + 4 + g < end) rB = edg2[start + 4 + g];
    for (int e = start; e < end; e += 8) {
        uint2 nA = make_uint2(0u, 0u), nB = make_uint2(0u, 0u);
        int pa = e + 8 + g, pb = e + 12 + g;
        if (pa < end) nA = edg2[pa];
        if (pb < end) nB = edg2[pb];
        if (rA.y) {
            int j = (int)rA.x;
            unsigned hv = h ? (rA.y >> 16) : (rA.y & 0xffffu);
            float w = __half2float(__ushort_as_half((unsigned short)hv));
            uint4 zz = *(const uint4*)(Z + (size_t)j * 128 + l4 * 8);
            a[0] += w * bflo(zz.x); a[1] += w * bfhi(zz.x);
            a[2] += w * bflo(zz.y); a[3] += w * bfhi(zz.y);
            a[4] += w * bflo(zz.z); a[5] += w * bfhi(zz.z);
            a[6] += w * bflo(zz.w); a[7] += w * bfhi(zz.w);
            ws += w;
        }
        if (rB.y) {
            int j = (int)rB.x;
            unsigned hv = h ? (rB.y >> 16) : (rB.y & 0xffffu);
            float w = __half2float(__ushort_as_half((unsigned short)hv));
            uint4 zz = *(const uint4*)(Z + (size_t)j * 128 + l4 * 8);
            a[0] += w * bflo(zz.x); a[1] += w * bfhi(zz.x);
            a[2] += w * bflo(zz.y); a[3] += w * bfhi(zz.y);
            a[4] += w * bflo(zz.z); a[5] += w * bfhi(zz.z);
            a[6] += w * bflo(zz.w); a[7] += w * bfhi(zz.w);
            ws += w;
        }
        rA = nA; rB = nB;
    }
#pragma unroll
    for (int i = 0; i < 8; ++i) {
        a[i] += __shfl_xor(a[i], 16);
        a[i] += __shfl_xor(a[i], 32);
    }
    ws += __shfl_xor(ws, 16);
    ws += __shfl_xor(ws, 32);
    float inv = 1.f / (ws + 1e-16f);
#pragma unroll
    for (int i = 0; i < 8; ++i) a[i] *= inv;
    // head combine: lane m (head0, out ch 8m..) pairs with lane m+8 (head1)
#pragma unroll
    for (int i = 0; i < 8; ++i) a[i] += __shfl_xor(a[i], 8);
    if (lane < 8) {
        float4 b0 = *(const float4*)&bias[lane * 8];
        float4 b1 = *(const float4*)&bias[lane * 8 + 4];
        float4 o0 = make_float4(a[0] + b0.x, a[1] + b0.y, a[2] + b0.z, a[3] + b0.w);
        float4 o1 = make_float4(a[4] + b1.x, a[5] + b1.y, a[6] + b1.z, a[7] + b1.w);
        *(float4*)&out[(size_t)node * 64 + lane * 8] = o0;
        *(float4*)&out[(size_t)node * 64 + lane * 8 + 4] = o1;
    }
}

// ---------------- launch ----------------
extern "C" void kernel_launch(void* const* d_in, const int* in_sizes, int n_in,
                              void* d_out, int out_size, void* d_ws, size_t ws_size,
                              hipStream_t stream)
{
    const float* x    = (const float*)d_in[0];
    const int*   ei   = (const int*)d_in[1];
    const float* Wl   = (const float*)d_in[2];
    const float* attL = (const float*)d_in[3];
    const float* attR = (const float*)d_in[4];
    const float* Wout = (const float*)d_in[5];
    const float* bias = (const float*)d_in[6];
    float* out = (float*)d_out;

    const int N = in_sizes[0] / 128;   // 50000
    const int E = in_sizes[1] / 2;     // 800000
    const int Etot = E + N;
    const int C = (N + 63) >> 6;       // 64-node chunks

    char* ws = (char*)d_ws;
    size_t o = 0;
    auto alloc = [&](size_t bytes) {
        void* p = ws + o; o += (bytes + 255) & ~(size_t)255; return p;
    };
    float*          Wc    = (float*)alloc(128 * 128 * 4);
    float*          AV    = (float*)alloc(128 * 4 * 4);
    unsigned short* Z     = (unsigned short*)alloc((size_t)N * 128 * 2);  // 12.8 MB
    float*          AL    = (float*)alloc((size_t)N * 2 * 4);
    float*          AR    = (float*)alloc((size_t)N * 2 * 4);
    int*            CNT   = (int*)alloc((size_t)N * 4);
    int*            OFF   = (int*)alloc((size_t)N * 4);
    int*            CHS   = (int*)alloc(256 * 4);
    int*            CBASE = (int*)alloc((size_t)(C + 1) * 4);
    int*            CPTR  = (int*)alloc((size_t)C * 16 * 4);   // line-padded cursors
    uint2*          EDG   = (uint2*)alloc((size_t)Etot * 8);   // bucketed records
    uint2*          EDG2  = (uint2*)alloc((size_t)Etot * 8);   // CSR-ordered records

    hipMemsetAsync(CNT, 0, (size_t)N * 4, stream);

    int eb = (Etot + 255) / 256;
    int nb = (N + 255) / 256;          // 196
    int ZB = (N + 63) / 64;            // 782

    prep_count_kernel<<<PREP_B + eb, 256, 0, stream>>>(Wl, Wout, attL, attR,
                                                       Wc, AV, ei, E, Etot, CNT);
    zproj_scan_kernel<<<ZB + nb, 256, 0, stream>>>(x, Wc, AV, N, ZB,
                                                   Z, AL, AR, CNT, OFF, CHS);
    scan2x<<<1, 256, 0, stream>>>(CHS, nb, N, Etot, OFF, CBASE, CPTR);
    fill2_kernel<<<eb, 256, 0, stream>>>(ei, E, Etot, AL, AR, CPTR, EDG);
    sort_kernel<<<C, 256, 0, stream>>>(CBASE, CHS, OFF, EDG, EDG2, N);
    agg_kernel<<<(N + 3) / 4, 256, 0, stream>>>(OFF, CHS, CNT, EDG2, Z, bias, out, N);
}

// Round 8
// 239.468 us; speedup vs baseline: 1.0977x; 1.0977x over previous
//
#include <hip/hip_runtime.h>

#define NEG_SLOPE 0.2f

static __device__ __forceinline__ unsigned short f2bf(float f) {
    unsigned u = __float_as_uint(f);
    unsigned r = (u + 0x7fffu + ((u >> 16) & 1u)) >> 16;   // RNE
    return (unsigned short)r;
}
static __device__ __forceinline__ float bflo(unsigned z) {
    return __uint_as_float((z & 0xffffu) << 16);
}
static __device__ __forceinline__ float bfhi(unsigned z) {
    return __uint_as_float(z & 0xffff0000u);
}

#define PREP_B 66   // blocks for prep part (128*128+512 = 16896 threads)

// ---- K1: prep (Wc, avec)  ||  count (degree histogram) ----
__global__ __launch_bounds__(256) void prep_count_kernel(
    const float* __restrict__ Wl, const float* __restrict__ Wout,
    const float* __restrict__ attL, const float* __restrict__ attR,
    float* __restrict__ Wc, float* __restrict__ avec,
    const int* __restrict__ ei, int E, int Etot, int* __restrict__ cnt)
{
    int bid = blockIdx.x;
    if (bid < PREP_B) {
        int idx = bid * 256 + threadIdx.x;
        if (idx < 128 * 128) {
            int k = idx >> 7, c = idx & 127;
            int h = c >> 6, cc = c & 63;
            const float* wl = Wl + k * 128 + h * 64;
            const float* wo = Wout + (h * 64) * 64 + cc;
            float s = 0.f;
#pragma unroll 8
            for (int m = 0; m < 64; ++m) s += wl[m] * wo[m * 64];
            Wc[k * 128 + c] = s;
        } else if (idx < 128 * 128 + 512) {
            int r = idx - 128 * 128;
            int k = r >> 2, t = r & 3;
            int h = t & 1;
            const float* av = ((t < 2) ? attL : attR) + h * 64;
            const float* wl = Wl + k * 128 + h * 64;
            float s = 0.f;
#pragma unroll 8
            for (int m = 0; m < 64; ++m) s += wl[m] * av[m];
            avec[k * 4 + t] = s;
        }
    } else {
        int e = (bid - PREP_B) * 256 + threadIdx.x;
        if (e >= Etot) return;
        int dst = (e < E) ? ei[E + e] : (e - E);
        atomicAdd(&cnt[dst], 1);
    }
}

// ---- K2: zproj (Z bf16, AL/AR)  ||  scan1 (per-256-chunk exclusive scan) ----
__global__ __launch_bounds__(256, 4) void zproj_scan_kernel(
    const float* __restrict__ x, const float* __restrict__ Wc,
    const float* __restrict__ avec, int N, int ZB,
    unsigned short* __restrict__ Z, float* __restrict__ AL, float* __restrict__ AR,
    const int* __restrict__ cnt, int* __restrict__ off, int* __restrict__ chs)
{
    __shared__ float xs[64 * 136];   // zproj x tile; scan1 reuses as int[256]
    __shared__ float avs[128 * 4];
    const int tid = threadIdx.x;

    if ((int)blockIdx.x >= ZB) {
        // ----- scan1 -----
        int blk = blockIdx.x - ZB;
        int* s = (int*)xs;
        int i = blk * 256 + tid;
        int v = (i < N) ? cnt[i] : 0;
        s[tid] = v; __syncthreads();
#pragma unroll
        for (int o = 1; o < 256; o <<= 1) {
            int add = (tid >= o) ? s[tid - o] : 0;
            __syncthreads();
            s[tid] += add;
            __syncthreads();
        }
        if (i < N) off[i] = s[tid] - v;     // exclusive within chunk
        if (tid == 255) chs[blk] = s[255];  // chunk total
        return;
    }

    // ----- zproj -----
    const int row0 = blockIdx.x * 64;
    const float4* x4 = (const float4*)x;
#pragma unroll
    for (int it = 0; it < 8; ++it) {
        int f4 = it * 256 + tid;           // 2048 float4 = 64 rows x 32 chunks
        int r = f4 >> 5, kq = f4 & 31;
        int rsrc = row0 + r; if (rsrc >= N) rsrc = N - 1;
        float4 v = x4[(size_t)rsrc * 32 + kq];
        *(float4*)&xs[r * 136 + kq * 4] = v;
    }
    if (tid < 128) *(float4*)&avs[tid * 4] = *(const float4*)&avec[tid * 4];
    __syncthreads();

    const int cg = tid & 31;   // cols cg*4..+3
    const int rg = tid >> 5;   // rows rg*8..+7
    const int c0 = cg * 4, r0 = rg * 8;
    float acc[8][4] = {};
    const float* wp = Wc + c0;
    for (int kc = 0; kc < 32; ++kc) {
        int k = kc * 4;
        float4 w0 = *(const float4*)&wp[(k + 0) * 128];
        float4 w1 = *(const float4*)&wp[(k + 1) * 128];
        float4 w2 = *(const float4*)&wp[(k + 2) * 128];
        float4 w3 = *(const float4*)&wp[(k + 3) * 128];
#pragma unroll
        for (int i = 0; i < 8; ++i) {
            float4 xv = *(const float4*)&xs[(r0 + i) * 136 + k];
            acc[i][0] += xv.x * w0.x + xv.y * w1.x + xv.z * w2.x + xv.w * w3.x;
            acc[i][1] += xv.x * w0.y + xv.y * w1.y + xv.z * w2.y + xv.w * w3.y;
            acc[i][2] += xv.x * w0.z + xv.y * w1.z + xv.z * w2.z + xv.w * w3.z;
            acc[i][3] += xv.x * w0.w + xv.y * w1.w + xv.z * w2.w + xv.w * w3.w;
        }
    }
#pragma unroll
    for (int i = 0; i < 8; ++i) {
        int row = row0 + r0 + i;
        if (row < N) {
            ushort4 zz;
            zz.x = f2bf(acc[i][0]); zz.y = f2bf(acc[i][1]);
            zz.z = f2bf(acc[i][2]); zz.w = f2bf(acc[i][3]);
            *(ushort4*)(Z + (size_t)row * 128 + c0) = zz;
        }
    }
    // alpha tail: one dot per thread (row = tid>>2, type = tid&3)
    {
        int row = tid >> 2, t = tid & 3;
        const float* xr = &xs[row * 136];
        float s = 0.f;
#pragma unroll 8
        for (int k = 0; k < 128; k += 4) {
            float4 xv = *(const float4*)&xr[k];
            s += xv.x * avs[(k + 0) * 4 + t] + xv.y * avs[(k + 1) * 4 + t]
               + xv.z * avs[(k + 2) * 4 + t] + xv.w * avs[(k + 3) * 4 + t];
        }
        int grow = row0 + row;
        if (grow < N) {
            if (t < 2) AL[grow * 2 + t] = s;
            else       AR[grow * 2 + (t - 2)] = s;
        }
    }
}

// ---- K3: scan of chunk totals (nb <= 256, single block) ----
__global__ __launch_bounds__(256) void scan2(int* __restrict__ chs, int nb)
{
    __shared__ int s[256];
    int t = threadIdx.x;
    int v = (t < nb) ? chs[t] : 0;
    s[t] = v; __syncthreads();
#pragma unroll
    for (int o = 1; o < 256; o <<= 1) {
        int add = (t >= o) ? s[t - o] : 0;
        __syncthreads();
        s[t] += add;
        __syncthreads();
    }
    if (t < nb) chs[t] = s[t] - v;   // exclusive chunk offsets
}

// ---- K4: fill — scatter 4B src into CSR position ----
__global__ void fill_kernel(const int* __restrict__ ei, int E, int Etot,
                            int* __restrict__ off, const int* __restrict__ chs,
                            int* __restrict__ srcs)
{
    int e = blockIdx.x * 256 + threadIdx.x;
    if (e >= Etot) return;
    int src, dst;
    if (e < E) { src = ei[e]; dst = ei[E + e]; }
    else       { src = e - E; dst = e - E; }
    int pos = atomicAdd(&off[dst], 1) + chs[dst >> 8];
    srcs[pos] = src;
}

// ---- K5: agg — wave/node, weights on the fly, 8 edges in flight ----
__global__ __launch_bounds__(256) void agg_kernel(
    const int* __restrict__ off, const int* __restrict__ chs,
    const int* __restrict__ cnt, const int* __restrict__ srcs,
    const float* __restrict__ AL, const float* __restrict__ AR,
    const unsigned short* __restrict__ Z, const float* __restrict__ bias,
    float* __restrict__ out, int N)
{
    int wid = threadIdx.x >> 6, lane = threadIdx.x & 63;
    int node = blockIdx.x * 4 + wid;
    if (node >= N) return;
    int end = chs[node >> 8] + off[node];   // off = local start+deg after fill
    int start = end - cnt[node];
    int g  = lane >> 4;              // edge slot 0..3
    int l4 = lane & 15;              // 16B chunk of the 256B Z row
    int h  = l4 >> 3;                // head owning these channels
    float arh = AR[node * 2 + h];
    float a[8] = {};
    float ws = 0.f;
    int last = end - 1;              // deg >= 1 always (self-loop)
    int sA = srcs[min(start + g, last)];
    int sB = srcs[min(start + 4 + g, last)];
    for (int e = start; e < end; e += 8) {
        int nsA = srcs[min(e + 8 + g, last)];
        int nsB = srcs[min(e + 12 + g, last)];
        // slot A
        {
            float al = AL[sA * 2 + h];
            float t = al + arh; t = (t < 0.f) ? NEG_SLOPE * t : t;
            float w = ((e + g) < end) ? __expf(t) : 0.f;
            uint4 zz = *(const uint4*)(Z + (size_t)sA * 128 + l4 * 8);
            a[0] += w * bflo(zz.x); a[1] += w * bfhi(zz.x);
            a[2] += w * bflo(zz.y); a[3] += w * bfhi(zz.y);
            a[4] += w * bflo(zz.z); a[5] += w * bfhi(zz.z);
            a[6] += w * bflo(zz.w); a[7] += w * bfhi(zz.w);
            ws += w;
        }
        // slot B
        {
            float al = AL[sB * 2 + h];
            float t = al + arh; t = (t < 0.f) ? NEG_SLOPE * t : t;
            float w = ((e + 4 + g) < end) ? __expf(t) : 0.f;
            uint4 zz = *(const uint4*)(Z + (size_t)sB * 128 + l4 * 8);
            a[0] += w * bflo(zz.x); a[1] += w * bfhi(zz.x);
            a[2] += w * bflo(zz.y); a[3] += w * bfhi(zz.y);
            a[4] += w * bflo(zz.z); a[5] += w * bfhi(zz.z);
            a[6] += w * bflo(zz.w); a[7] += w * bfhi(zz.w);
            ws += w;
        }
        sA = nsA; sB = nsB;
    }
#pragma unroll
    for (int i = 0; i < 8; ++i) {
        a[i] += __shfl_xor(a[i], 16);
        a[i] += __shfl_xor(a[i], 32);
    }
    ws += __shfl_xor(ws, 16);
    ws += __shfl_xor(ws, 32);
    float inv = 1.f / (ws + 1e-16f);
#pragma unroll
    for (int i = 0; i < 8; ++i) a[i] *= inv;
    // head combine: lane m (head0, out ch 8m..) pairs with lane m+8 (head1)
#pragma unroll
    for (int i = 0; i < 8; ++i) a[i] += __shfl_xor(a[i], 8);
    if (lane < 8) {
        float4 b0 = *(const float4*)&bias[lane * 8];
        float4 b1 = *(const float4*)&bias[lane * 8 + 4];
        float4 o0 = make_float4(a[0] + b0.x, a[1] + b0.y, a[2] + b0.z, a[3] + b0.w);
        float4 o1 = make_float4(a[4] + b1.x, a[5] + b1.y, a[6] + b1.z, a[7] + b1.w);
        *(float4*)&out[(size_t)node * 64 + lane * 8] = o0;
        *(float4*)&out[(size_t)node * 64 + lane * 8 + 4] = o1;
    }
}

// ---------------- launch ----------------
extern "C" void kernel_launch(void* const* d_in, const int* in_sizes, int n_in,
                              void* d_out, int out_size, void* d_ws, size_t ws_size,
                              hipStream_t stream)
{
    const float* x    = (const float*)d_in[0];
    const int*   ei   = (const int*)d_in[1];
    const float* Wl   = (const float*)d_in[2];
    const float* attL = (const float*)d_in[3];
    const float* attR = (const float*)d_in[4];
    const float* Wout = (const float*)d_in[5];
    const float* bias = (const float*)d_in[6];
    float* out = (float*)d_out;

    const int N = in_sizes[0] / 128;   // 50000
    const int E = in_sizes[1] / 2;     // 800000
    const int Etot = E + N;

    char* ws = (char*)d_ws;
    size_t o = 0;
    auto alloc = [&](size_t bytes) {
        void* p = ws + o; o += (bytes + 255) & ~(size_t)255; return p;
    };
    float*          Wc   = (float*)alloc(128 * 128 * 4);
    float*          AV   = (float*)alloc(128 * 4 * 4);
    unsigned short* Z    = (unsigned short*)alloc((size_t)N * 128 * 2);  // 12.8 MB
    float*          AL   = (float*)alloc((size_t)N * 2 * 4);
    float*          AR   = (float*)alloc((size_t)N * 2 * 4);
    int*            CNT  = (int*)alloc((size_t)N * 4);
    int*            OFF  = (int*)alloc((size_t)N * 4);
    int*            CHS  = (int*)alloc(256 * 4);
    int*            SRCS = (int*)alloc((size_t)Etot * 4);                // 3.4 MB

    hipMemsetAsync(CNT, 0, (size_t)N * 4, stream);

    int eb = (Etot + 255) / 256;
    int nb = (N + 255) / 256;          // 196
    int ZB = (N + 63) / 64;            // 782

    prep_count_kernel<<<PREP_B + eb, 256, 0, stream>>>(Wl, Wout, attL, attR,
                                                       Wc, AV, ei, E, Etot, CNT);
    zproj_scan_kernel<<<ZB + nb, 256, 0, stream>>>(x, Wc, AV, N, ZB,
                                                   Z, AL, AR, CNT, OFF, CHS);
    scan2<<<1, 256, 0, stream>>>(CHS, nb);
    fill_kernel<<<eb, 256, 0, stream>>>(ei, E, Etot, OFF, CHS, SRCS);
    agg_kernel<<<(N + 3) / 4, 256, 0, stream>>>(OFF, CHS, CNT, SRCS,
                                                AL, AR, Z, bias, out, N);
}